// Round 1
// baseline (6105.359 us; speedup 1.0000x reference)
//
#include <hip/hip_runtime.h>
#include <hip/hip_bf16.h>
#include <math.h>

#define IN_F   128
#define OUT_F  128
#define HEADS  8
#define HEAD_D 16
#define EDGE_F 64
#define NT     8   // nodes per block in node-GEMM kernels

// ---------------- QKV projection ----------------
// grid: ceil(N/NT) blocks x 128 threads. Thread = output column.
__global__ void qkv_kernel(const float* __restrict__ x,
                           const float* __restrict__ Wq, const float* __restrict__ bq,
                           const float* __restrict__ Wk, const float* __restrict__ bk,
                           const float* __restrict__ Wv, const float* __restrict__ bv,
                           float* __restrict__ q, float* __restrict__ k, float* __restrict__ v,
                           int n_nodes) {
    __shared__ float xs[NT][IN_F];
    const int col   = threadIdx.x;          // 0..127
    const int node0 = blockIdx.x * NT;

    #pragma unroll
    for (int n = 0; n < NT; ++n) {
        int node = node0 + n;
        xs[n][col] = (node < n_nodes) ? x[(size_t)node * IN_F + col] : 0.f;
    }
    __syncthreads();

    float accq[NT], acck[NT], accv[NT];
    #pragma unroll
    for (int n = 0; n < NT; ++n) { accq[n] = 0.f; acck[n] = 0.f; accv[n] = 0.f; }

    for (int kk = 0; kk < IN_F; ++kk) {
        float wq = Wq[kk * OUT_F + col];
        float wk = Wk[kk * OUT_F + col];
        float wv = Wv[kk * OUT_F + col];
        #pragma unroll
        for (int n = 0; n < NT; ++n) {
            float xv = xs[n][kk];
            accq[n] = fmaf(xv, wq, accq[n]);
            acck[n] = fmaf(xv, wk, acck[n]);
            accv[n] = fmaf(xv, wv, accv[n]);
        }
    }

    float bqv = bq[col], bkv = bk[col], bvv = bv[col];
    #pragma unroll
    for (int n = 0; n < NT; ++n) {
        int node = node0 + n;
        if (node < n_nodes) {
            size_t o = (size_t)node * OUT_F + col;
            q[o] = accq[n] + bqv;
            k[o] = acck[n] + bkv;
            v[o] = accv[n] + bvv;
        }
    }
}

// ---------------- Edge pass: scores + exp + atomic accumulate ----------------
// 1 thread per edge. denom[t,h] += w[h]; agg[t, h*16+d] += w[h]*v[s, h*16+d].
__global__ void edge_kernel(const int* __restrict__ ei,
                            const float* __restrict__ ef,
                            const float* __restrict__ q, const float* __restrict__ k,
                            const float* __restrict__ v,
                            const float* __restrict__ We, const float* __restrict__ be,
                            float* __restrict__ denom, float* __restrict__ agg,
                            int n_edges) {
    __shared__ float sWe[EDGE_F * HEADS];   // 2 KB
    __shared__ float sbe[HEADS];
    const int tid = threadIdx.x;
    for (int i = tid; i < EDGE_F * HEADS; i += 256) sWe[i] = We[i];
    if (tid < HEADS) sbe[tid] = be[tid];
    __syncthreads();

    const int e = blockIdx.x * 256 + tid;
    if (e >= n_edges) return;

    const int s = ei[e];
    const int t = ei[n_edges + e];

    const float4* qr = (const float4*)(q + (size_t)t * OUT_F);
    const float4* kr = (const float4*)(k + (size_t)s * OUT_F);

    float dots[HEADS];
    #pragma unroll
    for (int h = 0; h < HEADS; ++h) dots[h] = 0.f;
    #pragma unroll
    for (int i = 0; i < 32; ++i) {   // 4 float4 per head
        float4 a = qr[i];
        float4 b = kr[i];
        int h = i >> 2;
        dots[h] += a.x * b.x + a.y * b.y + a.z * b.z + a.w * b.w;
    }

    float bias[HEADS];
    #pragma unroll
    for (int h = 0; h < HEADS; ++h) bias[h] = sbe[h];
    const float4* efr = (const float4*)(ef + (size_t)e * EDGE_F);
    #pragma unroll
    for (int j4 = 0; j4 < EDGE_F / 4; ++j4) {
        float4 evv = efr[j4];
        float ev[4] = {evv.x, evv.y, evv.z, evv.w};
        #pragma unroll
        for (int jj = 0; jj < 4; ++jj) {
            int j = j4 * 4 + jj;
            #pragma unroll
            for (int h = 0; h < HEADS; ++h)
                bias[h] = fmaf(ev[jj], sWe[j * HEADS + h], bias[h]);
        }
    }

    const float scale = 0.25f;  // HEAD_D^-0.5 = 16^-0.5
    float w[HEADS];
    #pragma unroll
    for (int h = 0; h < HEADS; ++h) w[h] = __expf(fmaf(dots[h], scale, bias[h]));

    float* dden = denom + (size_t)t * HEADS;
    #pragma unroll
    for (int h = 0; h < HEADS; ++h) atomicAdd(dden + h, w[h]);

    const float4* vr = (const float4*)(v + (size_t)s * OUT_F);
    float* ag = agg + (size_t)t * OUT_F;
    #pragma unroll
    for (int i = 0; i < 32; ++i) {
        float4 vv = vr[i];
        float c = w[i >> 2];
        atomicAdd(ag + i * 4 + 0, c * vv.x);
        atomicAdd(ag + i * 4 + 1, c * vv.y);
        atomicAdd(ag + i * 4 + 2, c * vv.z);
        atomicAdd(ag + i * 4 + 3, c * vv.w);
    }
}

// ---------------- Output projection ----------------
__global__ void out_kernel(const float* __restrict__ agg, const float* __restrict__ denom,
                           const float* __restrict__ Wo, const float* __restrict__ bo,
                           float* __restrict__ out, int n_nodes) {
    __shared__ float xs[NT][OUT_F];
    const int col   = threadIdx.x;
    const int node0 = blockIdx.x * NT;

    #pragma unroll
    for (int n = 0; n < NT; ++n) {
        int node = node0 + n;
        float val = 0.f;
        if (node < n_nodes) {
            float d = denom[(size_t)node * HEADS + (col >> 4)] + 1e-10f;
            val = agg[(size_t)node * OUT_F + col] / d;
        }
        xs[n][col] = val;
    }
    __syncthreads();

    float acc[NT];
    #pragma unroll
    for (int n = 0; n < NT; ++n) acc[n] = 0.f;

    for (int kk = 0; kk < OUT_F; ++kk) {
        float wv = Wo[kk * OUT_F + col];
        #pragma unroll
        for (int n = 0; n < NT; ++n) acc[n] = fmaf(xs[n][kk], wv, acc[n]);
    }

    float b = bo[col];
    #pragma unroll
    for (int n = 0; n < NT; ++n) {
        int node = node0 + n;
        if (node < n_nodes) out[(size_t)node * OUT_F + col] = acc[n] + b;
    }
}

extern "C" void kernel_launch(void* const* d_in, const int* in_sizes, int n_in,
                              void* d_out, int out_size, void* d_ws, size_t ws_size,
                              hipStream_t stream) {
    const float* x  = (const float*)d_in[0];
    const int*   ei = (const int*)  d_in[1];
    const float* ef = (const float*)d_in[2];
    const float* Wq = (const float*)d_in[3];
    const float* bq = (const float*)d_in[4];
    const float* Wk = (const float*)d_in[5];
    const float* bk = (const float*)d_in[6];
    const float* Wv = (const float*)d_in[7];
    const float* bv = (const float*)d_in[8];
    const float* We = (const float*)d_in[9];
    const float* be = (const float*)d_in[10];
    const float* Wo = (const float*)d_in[11];
    const float* bo = (const float*)d_in[12];
    float* out = (float*)d_out;

    const int n_nodes = in_sizes[0] / IN_F;
    const int n_edges = in_sizes[1] / 2;

    float* ws    = (float*)d_ws;
    float* q     = ws;
    float* k     = q + (size_t)n_nodes * OUT_F;
    float* v     = k + (size_t)n_nodes * OUT_F;
    float* denom = v + (size_t)n_nodes * OUT_F;          // [N, HEADS]
    float* agg   = denom + (size_t)n_nodes * HEADS;      // [N, OUT_F]

    // zero denom + agg (contiguous)
    hipMemsetAsync(denom, 0,
                   ((size_t)n_nodes * HEADS + (size_t)n_nodes * OUT_F) * sizeof(float),
                   stream);

    dim3 nodeGrid((n_nodes + NT - 1) / NT);
    qkv_kernel<<<nodeGrid, 128, 0, stream>>>(x, Wq, bq, Wk, bk, Wv, bv, q, k, v, n_nodes);

    dim3 edgeGrid((n_edges + 255) / 256);
    edge_kernel<<<edgeGrid, 256, 0, stream>>>(ei, ef, q, k, v, We, be, denom, agg, n_edges);

    out_kernel<<<nodeGrid, 128, 0, stream>>>(agg, denom, Wo, bo, out, n_nodes);
}

// Round 2
// 938.146 us; speedup vs baseline: 6.5079x; 6.5079x over previous
//
#include <hip/hip_runtime.h>
#include <hip/hip_bf16.h>
#include <math.h>

#define IN_F   128
#define OUT_F  128
#define HEADS  8
#define HEAD_D 16
#define EDGE_F 64
#define NT     8      // nodes per block in node-GEMM kernels
#define EB_E   64     // edges per block in ebias kernel

// ---------------- QKV projection ----------------
__global__ void qkv_kernel(const float* __restrict__ x,
                           const float* __restrict__ Wq, const float* __restrict__ bq,
                           const float* __restrict__ Wk, const float* __restrict__ bk,
                           const float* __restrict__ Wv, const float* __restrict__ bv,
                           float* __restrict__ q, float* __restrict__ k, float* __restrict__ v,
                           int n_nodes) {
    __shared__ float xs[NT][IN_F];
    const int col   = threadIdx.x;          // 0..127
    const int node0 = blockIdx.x * NT;

    #pragma unroll
    for (int n = 0; n < NT; ++n) {
        int node = node0 + n;
        xs[n][col] = (node < n_nodes) ? x[(size_t)node * IN_F + col] : 0.f;
    }
    __syncthreads();

    float accq[NT], acck[NT], accv[NT];
    #pragma unroll
    for (int n = 0; n < NT; ++n) { accq[n] = 0.f; acck[n] = 0.f; accv[n] = 0.f; }

    for (int kk = 0; kk < IN_F; ++kk) {
        float wq = Wq[kk * OUT_F + col];
        float wk = Wk[kk * OUT_F + col];
        float wv = Wv[kk * OUT_F + col];
        #pragma unroll
        for (int n = 0; n < NT; ++n) {
            float xv = xs[n][kk];
            accq[n] = fmaf(xv, wq, accq[n]);
            acck[n] = fmaf(xv, wk, acck[n]);
            accv[n] = fmaf(xv, wv, accv[n]);
        }
    }

    float bqv = bq[col], bkv = bk[col], bvv = bv[col];
    #pragma unroll
    for (int n = 0; n < NT; ++n) {
        int node = node0 + n;
        if (node < n_nodes) {
            size_t o = (size_t)node * OUT_F + col;
            q[o] = accq[n] + bqv;
            k[o] = acck[n] + bkv;
            v[o] = accv[n] + bvv;
        }
    }
}

// ---------------- Edge bias: ebias[e,h] = ef[e,:] @ We[:,h] + be[h] ----------------
__global__ void ebias_kernel(const float* __restrict__ ef,
                             const float* __restrict__ We, const float* __restrict__ be,
                             float* __restrict__ ebias, int n_edges) {
    __shared__ float sef[EB_E][EDGE_F + 1];
    __shared__ float sWe[EDGE_F * HEADS];
    __shared__ float sbe[HEADS];
    const int tid = threadIdx.x;           // 0..255
    const int e0  = blockIdx.x * EB_E;

    for (int i = tid; i < EDGE_F * HEADS; i += 256) sWe[i] = We[i];
    if (tid < HEADS) sbe[tid] = be[tid];
    for (int i = tid; i < EB_E * EDGE_F; i += 256) {
        int r = i >> 6, c = i & 63;
        int e = e0 + r;
        sef[r][c] = (e < n_edges) ? ef[(size_t)e * EDGE_F + c] : 0.f;
    }
    __syncthreads();

    for (int o = tid; o < EB_E * HEADS; o += 256) {
        int r = o >> 3, h = o & 7;
        int e = e0 + r;
        if (e < n_edges) {
            float acc = sbe[h];
            #pragma unroll
            for (int j = 0; j < EDGE_F; ++j)
                acc = fmaf(sef[r][j], sWe[j * HEADS + h], acc);
            ebias[(size_t)e * HEADS + h] = acc;
        }
    }
}

// ---------------- CSR build ----------------
__global__ void count_kernel(const int* __restrict__ ei, int* __restrict__ deg, int n_edges) {
    int e = blockIdx.x * 256 + threadIdx.x;
    if (e < n_edges) atomicAdd(&deg[ei[n_edges + e]], 1);
}

// single block, 1024 threads: exclusive scan of deg -> rowstart, cursor
__global__ void scan_kernel(const int* __restrict__ deg, int* __restrict__ rowstart,
                            int* __restrict__ cursor, int n_nodes, int n_edges) {
    __shared__ int part[1024];
    const int tid = threadIdx.x;
    const int C = (n_nodes + 1023) / 1024;
    int begin = tid * C;
    int end   = begin + C; if (end > n_nodes) end = n_nodes;
    if (begin > n_nodes) begin = n_nodes;

    int s = 0;
    for (int i = begin; i < end; ++i) s += deg[i];
    part[tid] = s;
    __syncthreads();

    for (int off = 1; off < 1024; off <<= 1) {
        int val = (tid >= off) ? part[tid - off] : 0;
        __syncthreads();
        part[tid] += val;
        __syncthreads();
    }

    int run = part[tid] - s;   // exclusive prefix for this chunk
    for (int i = begin; i < end; ++i) {
        rowstart[i] = run;
        cursor[i]   = run;
        run += deg[i];
    }
    if (tid == 0) rowstart[n_nodes] = n_edges;
}

__global__ void scatter_kernel(const int* __restrict__ ei, int* __restrict__ cursor,
                               int* __restrict__ csr, int n_edges) {
    int e = blockIdx.x * 256 + threadIdx.x;
    if (e < n_edges) {
        int t = ei[n_edges + e];
        int pos = atomicAdd(&cursor[t], 1);
        csr[pos] = e;
    }
}

// ---------------- Aggregation: one block (128 thr) per target node, no atomics ----
__global__ void agg_kernel(const int* __restrict__ ei, const int* __restrict__ csr,
                           const int* __restrict__ rowstart,
                           const float* __restrict__ q, const float* __restrict__ k,
                           const float* __restrict__ v, const float* __restrict__ ebias,
                           float* __restrict__ aggn, int n_edges) {
    const int t   = blockIdx.x;
    const int tid = threadIdx.x;        // 0..127, feature index
    const int h   = tid >> 4;           // head
    const float qj = q[(size_t)t * OUT_F + tid];

    const int beg = rowstart[t];
    const int end = rowstart[t + 1];

    float acc = 0.f, den = 0.f;

    int i = beg;
    int   s  = 0;
    float kv = 0.f, vv = 0.f, eb = 0.f;
    if (i < end) {
        int e = csr[i];
        s  = ei[e];
        kv = k[(size_t)s * OUT_F + tid];
        vv = v[(size_t)s * OUT_F + tid];
        eb = ebias[(size_t)e * HEADS + h];
    }
    while (i < end) {
        float p    = qj * kv;
        float vcur = vv;
        float ebc  = eb;
        int inext  = i + 1;
        if (inext < end) {               // prefetch next edge
            int e2 = csr[inext];
            int s2 = ei[e2];
            kv = k[(size_t)s2 * OUT_F + tid];
            vv = v[(size_t)s2 * OUT_F + tid];
            eb = ebias[(size_t)e2 * HEADS + h];
        }
        p += __shfl_xor(p, 8, 16);
        p += __shfl_xor(p, 4, 16);
        p += __shfl_xor(p, 2, 16);
        p += __shfl_xor(p, 1, 16);
        float w = __expf(fmaf(p, 0.25f, ebc));   // scale = 16^-0.5
        den += w;                                // w uniform within head group
        acc = fmaf(w, vcur, acc);
        i = inext;
    }
    aggn[(size_t)t * OUT_F + tid] = acc / (den + 1e-10f);
}

// ---------------- Output projection (reads aggn from d_out in-place safe) -------
__global__ void out_kernel(const float* __restrict__ aggn,
                           const float* __restrict__ Wo, const float* __restrict__ bo,
                           float* __restrict__ out, int n_nodes) {
    __shared__ float xs[NT][OUT_F];
    const int col   = threadIdx.x;
    const int node0 = blockIdx.x * NT;

    #pragma unroll
    for (int n = 0; n < NT; ++n) {
        int node = node0 + n;
        xs[n][col] = (node < n_nodes) ? aggn[(size_t)node * OUT_F + col] : 0.f;
    }
    __syncthreads();

    float acc[NT];
    #pragma unroll
    for (int n = 0; n < NT; ++n) acc[n] = 0.f;

    for (int kk = 0; kk < OUT_F; ++kk) {
        float wv = Wo[kk * OUT_F + col];
        #pragma unroll
        for (int n = 0; n < NT; ++n) acc[n] = fmaf(xs[n][kk], wv, acc[n]);
    }

    float b = bo[col];
    #pragma unroll
    for (int n = 0; n < NT; ++n) {
        int node = node0 + n;
        if (node < n_nodes) out[(size_t)node * OUT_F + col] = acc[n] + b;
    }
}

extern "C" void kernel_launch(void* const* d_in, const int* in_sizes, int n_in,
                              void* d_out, int out_size, void* d_ws, size_t ws_size,
                              hipStream_t stream) {
    const float* x  = (const float*)d_in[0];
    const int*   ei = (const int*)  d_in[1];
    const float* ef = (const float*)d_in[2];
    const float* Wq = (const float*)d_in[3];
    const float* bq = (const float*)d_in[4];
    const float* Wk = (const float*)d_in[5];
    const float* bk = (const float*)d_in[6];
    const float* Wv = (const float*)d_in[7];
    const float* bv = (const float*)d_in[8];
    const float* We = (const float*)d_in[9];
    const float* be = (const float*)d_in[10];
    const float* Wo = (const float*)d_in[11];
    const float* bo = (const float*)d_in[12];
    float* out = (float*)d_out;

    const int n_nodes = in_sizes[0] / IN_F;
    const int n_edges = in_sizes[1] / 2;

    float* ws    = (float*)d_ws;
    float* q     = ws;
    float* k     = q + (size_t)n_nodes * OUT_F;
    float* v     = k + (size_t)n_nodes * OUT_F;
    float* ebias = v + (size_t)n_nodes * OUT_F;             // [E, HEADS]
    int*   deg      = (int*)(ebias + (size_t)n_edges * HEADS);
    int*   rowstart = deg + n_nodes;                        // [N+1]
    int*   cursor   = rowstart + n_nodes + 1;               // [N]
    int*   csr      = cursor + n_nodes;                     // [E]

    hipMemsetAsync(deg, 0, (size_t)n_nodes * sizeof(int), stream);

    dim3 nodeGrid((n_nodes + NT - 1) / NT);
    qkv_kernel<<<nodeGrid, 128, 0, stream>>>(x, Wq, bq, Wk, bk, Wv, bv, q, k, v, n_nodes);

    ebias_kernel<<<(n_edges + EB_E - 1) / EB_E, 256, 0, stream>>>(ef, We, be, ebias, n_edges);

    dim3 edgeGrid((n_edges + 255) / 256);
    count_kernel<<<edgeGrid, 256, 0, stream>>>(ei, deg, n_edges);
    scan_kernel<<<1, 1024, 0, stream>>>(deg, rowstart, cursor, n_nodes, n_edges);
    scatter_kernel<<<edgeGrid, 256, 0, stream>>>(ei, cursor, csr, n_edges);

    // aggn written into d_out (scratch); out_kernel reads-then-overwrites safely
    agg_kernel<<<n_nodes, 128, 0, stream>>>(ei, csr, rowstart, q, k, v, ebias, out, n_edges);

    out_kernel<<<nodeGrid, 128, 0, stream>>>(out, Wo, bo, out, n_nodes);
}

// Round 3
// 936.724 us; speedup vs baseline: 6.5178x; 1.0015x over previous
//
#include <hip/hip_runtime.h>
#include <hip/hip_bf16.h>
#include <math.h>

#define IN_F   128
#define OUT_F  128
#define HEADS  8
#define HEAD_D 16
#define EDGE_F 64
#define NTQ    16     // nodes per block in qkv kernel
#define NTO    32     // nodes per block in out kernel

// round-to-nearest-even fp32 -> bf16 bits
__device__ inline unsigned int f2bf(float f) {
    union { float f; unsigned int u; } c; c.f = f;
    unsigned int r = c.u + 0x7FFFu + ((c.u >> 16) & 1u);
    return r >> 16;
}

// ---------------- QKV projection: q fp32, k/v packed bf16 ----------------
__global__ __launch_bounds__(128)
void qkv_kernel(const float* __restrict__ x,
                const float* __restrict__ Wq, const float* __restrict__ bq,
                const float* __restrict__ Wk, const float* __restrict__ bk,
                const float* __restrict__ Wv, const float* __restrict__ bv,
                float* __restrict__ q, unsigned int* __restrict__ kvp,
                int n_nodes) {
    __shared__ float xs[NTQ][IN_F];
    const int col   = threadIdx.x;          // 0..127
    const int node0 = blockIdx.x * NTQ;

    #pragma unroll
    for (int n = 0; n < NTQ; ++n) {
        int node = node0 + n;
        xs[n][col] = (node < n_nodes) ? x[(size_t)node * IN_F + col] : 0.f;
    }
    __syncthreads();

    float accq[NTQ], acck[NTQ], accv[NTQ];
    #pragma unroll
    for (int n = 0; n < NTQ; ++n) { accq[n] = 0.f; acck[n] = 0.f; accv[n] = 0.f; }

    for (int kk = 0; kk < IN_F; ++kk) {
        float wq = Wq[kk * OUT_F + col];
        float wk = Wk[kk * OUT_F + col];
        float wv = Wv[kk * OUT_F + col];
        #pragma unroll
        for (int n = 0; n < NTQ; ++n) {
            float xv = xs[n][kk];
            accq[n] = fmaf(xv, wq, accq[n]);
            acck[n] = fmaf(xv, wk, acck[n]);
            accv[n] = fmaf(xv, wv, accv[n]);
        }
    }

    float bqv = bq[col], bkv = bk[col], bvv = bv[col];
    #pragma unroll
    for (int n = 0; n < NTQ; ++n) {
        int node = node0 + n;
        if (node < n_nodes) {
            size_t o = (size_t)node * OUT_F + col;
            q[o] = accq[n] + bqv;
            kvp[o] = f2bf(acck[n] + bkv) | (f2bf(accv[n] + bvv) << 16);
        }
    }
}

// ---------------- Edge bias: 1 thread per edge, LDS-staged ef ----------------
__global__ __launch_bounds__(128)
void ebias_kernel(const float* __restrict__ ef,
                  const float* __restrict__ We, const float* __restrict__ be,
                  float* __restrict__ ebias, int n_edges) {
    __shared__ float sef[128][EDGE_F + 1];   // +1 pad: conflict-free row reads
    __shared__ float sWe[EDGE_F * HEADS];
    __shared__ float sbe[HEADS];
    const int tid = threadIdx.x;             // 0..127
    const int e0  = blockIdx.x * 128;

    for (int i = tid; i < EDGE_F * HEADS; i += 128) sWe[i] = We[i];
    if (tid < HEADS) sbe[tid] = be[tid];
    for (int i = tid; i < 128 * EDGE_F; i += 128) {
        int r = i >> 6, c = i & 63;
        sef[r][c] = (e0 + r < n_edges) ? ef[(size_t)e0 * EDGE_F + i] : 0.f;
    }
    __syncthreads();

    const int e = e0 + tid;
    if (e < n_edges) {
        float acc[HEADS];
        #pragma unroll
        for (int h = 0; h < HEADS; ++h) acc[h] = sbe[h];
        for (int j = 0; j < EDGE_F; ++j) {
            float sv = sef[tid][j];                  // conflict-free (pad)
            #pragma unroll
            for (int h = 0; h < HEADS; ++h)
                acc[h] = fmaf(sv, sWe[j * HEADS + h], acc[h]);  // broadcast
        }
        float4* dst = (float4*)(ebias + (size_t)e * HEADS);
        dst[0] = make_float4(acc[0], acc[1], acc[2], acc[3]);
        dst[1] = make_float4(acc[4], acc[5], acc[6], acc[7]);
    }
}

// ---------------- CSR build ----------------
__global__ __launch_bounds__(256)
void count_kernel(const int* __restrict__ ei, int* __restrict__ deg, int n_edges) {
    int e = blockIdx.x * 256 + threadIdx.x;
    if (e < n_edges) atomicAdd(&deg[ei[n_edges + e]], 1);
}

// single block, 1024 threads: coalesced chunked scan via wave shuffles
__global__ __launch_bounds__(1024)
void scan_kernel(const int* __restrict__ deg, int* __restrict__ rowstart,
                 int* __restrict__ cursor, int n_nodes, int n_edges) {
    __shared__ int wsums[16];
    const int tid  = threadIdx.x;
    const int lane = tid & 63;
    const int wid  = tid >> 6;
    int carry = 0;

    for (int base = 0; base < n_nodes; base += 1024) {
        int idx = base + tid;
        int d = (idx < n_nodes) ? deg[idx] : 0;
        // inclusive wave scan
        int xv = d;
        #pragma unroll
        for (int off = 1; off < 64; off <<= 1) {
            int y = __shfl_up(xv, off, 64);
            if (lane >= off) xv += y;
        }
        if (lane == 63) wsums[wid] = xv;
        __syncthreads();
        if (wid == 0 && lane < 16) {
            int w = wsums[lane];
            #pragma unroll
            for (int off = 1; off < 16; off <<= 1) {
                int y = __shfl_up(w, off, 16);
                if (lane >= off) w += y;
            }
            wsums[lane] = w;
        }
        __syncthreads();
        int pre = carry + (wid > 0 ? wsums[wid - 1] : 0) + xv - d;  // exclusive
        if (idx < n_nodes) { rowstart[idx] = pre; cursor[idx] = pre; }
        carry += wsums[15];
        __syncthreads();   // protect wsums before next iteration
    }
    if (tid == 0) rowstart[n_nodes] = n_edges;
}

__global__ __launch_bounds__(256)
void scatter_kernel(const int* __restrict__ ei, int* __restrict__ cursor,
                    int2* __restrict__ csr2, int n_edges) {
    int e = blockIdx.x * 256 + threadIdx.x;
    if (e < n_edges) {
        int s = ei[e];
        int t = ei[n_edges + e];
        int pos = atomicAdd(&cursor[t], 1);
        csr2[pos] = make_int2(s, e);
    }
}

// ---------------- Aggregation: one block (128 thr) per target node ----------------
__global__ __launch_bounds__(128)
void agg_kernel(const int2* __restrict__ csr2, const int* __restrict__ rowstart,
                const float* __restrict__ q, const unsigned int* __restrict__ kvp,
                const float* __restrict__ ebias, float* __restrict__ aggn) {
    const int t   = blockIdx.x;
    const int tid = threadIdx.x;        // feature index 0..127
    const int h   = tid >> 4;           // head
    const float qj = q[(size_t)t * OUT_F + tid];

    const int beg = rowstart[t];
    const int end = rowstart[t + 1];

    float acc = 0.f, den = 0.f;

    int i = beg;
    unsigned int kvw = 0;
    float eb = 0.f;
    if (i < end) {
        int2 se = csr2[i];
        kvw = kvp[(size_t)se.x * OUT_F + tid];
        eb  = ebias[(size_t)se.y * HEADS + h];
    }
    while (i < end) {
        float kf  = __uint_as_float(kvw << 16);
        float vf  = __uint_as_float(kvw & 0xFFFF0000u);
        float ebc = eb;
        int inext = i + 1;
        if (inext < end) {               // prefetch next edge
            int2 se2 = csr2[inext];
            kvw = kvp[(size_t)se2.x * OUT_F + tid];
            eb  = ebias[(size_t)se2.y * HEADS + h];
        }
        float p = qj * kf;
        p += __shfl_xor(p, 8, 16);
        p += __shfl_xor(p, 4, 16);
        p += __shfl_xor(p, 2, 16);
        p += __shfl_xor(p, 1, 16);
        float w = __expf(fmaf(p, 0.25f, ebc));   // scale = 16^-0.5
        den += w;
        acc = fmaf(w, vf, acc);
        i = inext;
    }
    aggn[(size_t)t * OUT_F + tid] = acc / (den + 1e-10f);
}

// ---------------- Output projection (in-place on d_out, per-block rows) ----------
__global__ __launch_bounds__(128)
void out_kernel(const float* __restrict__ aggn,
                const float* __restrict__ Wo, const float* __restrict__ bo,
                float* __restrict__ out, int n_nodes) {
    __shared__ float xs[NTO][OUT_F];
    const int col   = threadIdx.x;
    const int node0 = blockIdx.x * NTO;

    #pragma unroll
    for (int n = 0; n < NTO; ++n) {
        int node = node0 + n;
        xs[n][col] = (node < n_nodes) ? aggn[(size_t)node * OUT_F + col] : 0.f;
    }
    __syncthreads();

    float acc[NTO];
    #pragma unroll
    for (int n = 0; n < NTO; ++n) acc[n] = 0.f;

    for (int kk = 0; kk < OUT_F; ++kk) {
        float wv = Wo[kk * OUT_F + col];
        #pragma unroll
        for (int n = 0; n < NTO; ++n) acc[n] = fmaf(xs[n][kk], wv, acc[n]);
    }

    float b = bo[col];
    #pragma unroll
    for (int n = 0; n < NTO; ++n) {
        int node = node0 + n;
        if (node < n_nodes) out[(size_t)node * OUT_F + col] = acc[n] + b;
    }
}

extern "C" void kernel_launch(void* const* d_in, const int* in_sizes, int n_in,
                              void* d_out, int out_size, void* d_ws, size_t ws_size,
                              hipStream_t stream) {
    const float* x  = (const float*)d_in[0];
    const int*   ei = (const int*)  d_in[1];
    const float* ef = (const float*)d_in[2];
    const float* Wq = (const float*)d_in[3];
    const float* bq = (const float*)d_in[4];
    const float* Wk = (const float*)d_in[5];
    const float* bk = (const float*)d_in[6];
    const float* Wv = (const float*)d_in[7];
    const float* bv = (const float*)d_in[8];
    const float* We = (const float*)d_in[9];
    const float* be = (const float*)d_in[10];
    const float* Wo = (const float*)d_in[11];
    const float* bo = (const float*)d_in[12];
    float* out = (float*)d_out;

    const int n_nodes = in_sizes[0] / IN_F;
    const int n_edges = in_sizes[1] / 2;

    float*        ws    = (float*)d_ws;
    float*        q     = ws;                                        // [N,128] f32
    unsigned int* kvp   = (unsigned int*)(q + (size_t)n_nodes * OUT_F); // [N,128] packed bf16 k|v
    float*        ebias = (float*)(kvp + (size_t)n_nodes * OUT_F);   // [E,8] f32
    int*          deg      = (int*)(ebias + (size_t)n_edges * HEADS);
    int*          rowstart = deg + n_nodes;                          // [N+1]
    int*          cursor   = rowstart + n_nodes + 1;                 // [N]
    int2*         csr2     = (int2*)(cursor + n_nodes);              // [E] (src, edge)

    hipMemsetAsync(deg, 0, (size_t)n_nodes * sizeof(int), stream);

    qkv_kernel<<<(n_nodes + NTQ - 1) / NTQ, 128, 0, stream>>>(
        x, Wq, bq, Wk, bk, Wv, bv, q, kvp, n_nodes);

    ebias_kernel<<<(n_edges + 127) / 128, 128, 0, stream>>>(ef, We, be, ebias, n_edges);

    dim3 edgeGrid((n_edges + 255) / 256);
    count_kernel<<<edgeGrid, 256, 0, stream>>>(ei, deg, n_edges);
    scan_kernel<<<1, 1024, 0, stream>>>(deg, rowstart, cursor, n_nodes, n_edges);
    scatter_kernel<<<edgeGrid, 256, 0, stream>>>(ei, cursor, csr2, n_edges);

    // aggn written into d_out (scratch); out_kernel reads-then-overwrites per block
    agg_kernel<<<n_nodes, 128, 0, stream>>>(csr2, rowstart, q, kvp, ebias, out);

    out_kernel<<<(n_nodes + NTO - 1) / NTO, 128, 0, stream>>>(out, Wo, bo, out, n_nodes);
}

// Round 4
// 730.933 us; speedup vs baseline: 8.3528x; 1.2815x over previous
//
#include <hip/hip_runtime.h>
#include <hip/hip_bf16.h>
#include <math.h>

#define IN_F   128
#define OUT_F  128
#define HEADS  8
#define HEAD_D 16
#define EDGE_F 64
#define NTQ    16     // nodes per block in qkv kernel
#define NTO    32     // nodes per block in out kernel

// round-to-nearest-even fp32 -> bf16 bits
__device__ inline unsigned int f2bf(float f) {
    union { float f; unsigned int u; } c; c.f = f;
    unsigned int r = c.u + 0x7FFFu + ((c.u >> 16) & 1u);
    return r >> 16;
}

// ---------------- QKV projection: q fp32, k/v packed bf16 ----------------
__global__ __launch_bounds__(128)
void qkv_kernel(const float* __restrict__ x,
                const float* __restrict__ Wq, const float* __restrict__ bq,
                const float* __restrict__ Wk, const float* __restrict__ bk,
                const float* __restrict__ Wv, const float* __restrict__ bv,
                float* __restrict__ q, unsigned int* __restrict__ kvp,
                int n_nodes) {
    __shared__ float xs[NTQ][IN_F];
    const int col   = threadIdx.x;          // 0..127
    const int node0 = blockIdx.x * NTQ;

    #pragma unroll
    for (int n = 0; n < NTQ; ++n) {
        int node = node0 + n;
        xs[n][col] = (node < n_nodes) ? x[(size_t)node * IN_F + col] : 0.f;
    }
    __syncthreads();

    float accq[NTQ], acck[NTQ], accv[NTQ];
    #pragma unroll
    for (int n = 0; n < NTQ; ++n) { accq[n] = 0.f; acck[n] = 0.f; accv[n] = 0.f; }

    for (int kk = 0; kk < IN_F; ++kk) {
        float wq = Wq[kk * OUT_F + col];
        float wk = Wk[kk * OUT_F + col];
        float wv = Wv[kk * OUT_F + col];
        #pragma unroll
        for (int n = 0; n < NTQ; ++n) {
            float xv = xs[n][kk];
            accq[n] = fmaf(xv, wq, accq[n]);
            acck[n] = fmaf(xv, wk, acck[n]);
            accv[n] = fmaf(xv, wv, accv[n]);
        }
    }

    float bqv = bq[col], bkv = bk[col], bvv = bv[col];
    #pragma unroll
    for (int n = 0; n < NTQ; ++n) {
        int node = node0 + n;
        if (node < n_nodes) {
            size_t o = (size_t)node * OUT_F + col;
            q[o] = accq[n] + bqv;
            kvp[o] = f2bf(acck[n] + bkv) | (f2bf(accv[n] + bvv) << 16);
        }
    }
}

// ---------------- Edge bias: 1 thread/edge, direct float4 reads, no ef staging ----
__global__ __launch_bounds__(256)
void ebias_kernel(const float* __restrict__ ef,
                  const float* __restrict__ We, const float* __restrict__ be,
                  float* __restrict__ ebias, int n_edges) {
    __shared__ float sWe[EDGE_F * HEADS];   // 2 KB
    __shared__ float sbe[HEADS];
    const int tid = threadIdx.x;
    for (int i = tid; i < EDGE_F * HEADS; i += 256) sWe[i] = We[i];
    if (tid < HEADS) sbe[tid] = be[tid];
    __syncthreads();

    const int e = blockIdx.x * 256 + tid;
    if (e >= n_edges) return;

    float acc[HEADS];
    #pragma unroll
    for (int h = 0; h < HEADS; ++h) acc[h] = sbe[h];

    const float4* er = (const float4*)(ef + (size_t)e * EDGE_F);
    #pragma unroll
    for (int j4 = 0; j4 < EDGE_F / 4; ++j4) {
        float4 evv = er[j4];
        float ev[4] = {evv.x, evv.y, evv.z, evv.w};
        #pragma unroll
        for (int jj = 0; jj < 4; ++jj) {
            int j = j4 * 4 + jj;
            #pragma unroll
            for (int h = 0; h < HEADS; ++h)
                acc[h] = fmaf(ev[jj], sWe[j * HEADS + h], acc[h]);  // broadcast read
        }
    }

    float4* dst = (float4*)(ebias + (size_t)e * HEADS);
    dst[0] = make_float4(acc[0], acc[1], acc[2], acc[3]);
    dst[1] = make_float4(acc[4], acc[5], acc[6], acc[7]);
}

// ---------------- CSR build ----------------
__global__ __launch_bounds__(256)
void count_kernel(const int* __restrict__ ei, int* __restrict__ deg, int n_edges) {
    int e = blockIdx.x * 256 + threadIdx.x;
    if (e < n_edges) atomicAdd(&deg[ei[n_edges + e]], 1);
}

// single block, 1024 threads: coalesced chunked scan via wave shuffles
__global__ __launch_bounds__(1024)
void scan_kernel(const int* __restrict__ deg, int* __restrict__ rowstart,
                 int* __restrict__ cursor, int n_nodes, int n_edges) {
    __shared__ int wsums[16];
    const int tid  = threadIdx.x;
    const int lane = tid & 63;
    const int wid  = tid >> 6;
    int carry = 0;

    for (int base = 0; base < n_nodes; base += 1024) {
        int idx = base + tid;
        int d = (idx < n_nodes) ? deg[idx] : 0;
        int xv = d;
        #pragma unroll
        for (int off = 1; off < 64; off <<= 1) {
            int y = __shfl_up(xv, off, 64);
            if (lane >= off) xv += y;
        }
        if (lane == 63) wsums[wid] = xv;
        __syncthreads();
        if (wid == 0 && lane < 16) {
            int w = wsums[lane];
            #pragma unroll
            for (int off = 1; off < 16; off <<= 1) {
                int y = __shfl_up(w, off, 16);
                if (lane >= off) w += y;
            }
            wsums[lane] = w;
        }
        __syncthreads();
        int pre = carry + (wid > 0 ? wsums[wid - 1] : 0) + xv - d;  // exclusive
        if (idx < n_nodes) { rowstart[idx] = pre; cursor[idx] = pre; }
        carry += wsums[15];
        __syncthreads();
    }
    if (tid == 0) rowstart[n_nodes] = n_edges;
}

__global__ __launch_bounds__(256)
void scatter_kernel(const int* __restrict__ ei, int* __restrict__ cursor,
                    int2* __restrict__ csr2, int n_edges) {
    int e = blockIdx.x * 256 + threadIdx.x;
    if (e < n_edges) {
        int s = ei[e];
        int t = ei[n_edges + e];
        int pos = atomicAdd(&cursor[t], 1);
        csr2[pos] = make_int2(s, e);
    }
}

// ---------------- Aggregation: one block per target, 2-edge software pipeline ----
__global__ __launch_bounds__(128)
void agg_kernel(const int2* __restrict__ csr2, const int* __restrict__ rowstart,
                const float* __restrict__ q, const unsigned int* __restrict__ kvp,
                const float* __restrict__ ebias, float* __restrict__ aggn) {
    const int t   = blockIdx.x;
    const int tid = threadIdx.x;        // feature index 0..127
    const int h   = tid >> 4;           // head
    const float qj = q[(size_t)t * OUT_F + tid];

    const int beg = rowstart[t];
    const int end = rowstart[t + 1];

    float acc = 0.f, den = 0.f;

    unsigned int kvw0 = 0, kvw1 = 0;
    float eb0 = 0.f, eb1 = 0.f;
    if (beg < end) {
        int2 se = csr2[beg];
        kvw0 = kvp[(size_t)se.x * OUT_F + tid];
        eb0  = ebias[(size_t)se.y * HEADS + h];
    }
    if (beg + 1 < end) {
        int2 se = csr2[beg + 1];
        kvw1 = kvp[(size_t)se.x * OUT_F + tid];
        eb1  = ebias[(size_t)se.y * HEADS + h];
    }

    int i = beg;
    while (i + 1 < end) {
        unsigned int nkv0 = 0, nkv1 = 0;
        float neb0 = 0.f, neb1 = 0.f;
        if (i + 2 < end) {
            int2 se = csr2[i + 2];
            nkv0 = kvp[(size_t)se.x * OUT_F + tid];
            neb0 = ebias[(size_t)se.y * HEADS + h];
        }
        if (i + 3 < end) {
            int2 se = csr2[i + 3];
            nkv1 = kvp[(size_t)se.x * OUT_F + tid];
            neb1 = ebias[(size_t)se.y * HEADS + h];
        }
        // edge i
        {
            float kf = __uint_as_float(kvw0 << 16);
            float vf = __uint_as_float(kvw0 & 0xFFFF0000u);
            float p = qj * kf;
            p += __shfl_xor(p, 8, 16);
            p += __shfl_xor(p, 4, 16);
            p += __shfl_xor(p, 2, 16);
            p += __shfl_xor(p, 1, 16);
            float w = __expf(fmaf(p, 0.25f, eb0));
            den += w;
            acc = fmaf(w, vf, acc);
        }
        // edge i+1
        {
            float kf = __uint_as_float(kvw1 << 16);
            float vf = __uint_as_float(kvw1 & 0xFFFF0000u);
            float p = qj * kf;
            p += __shfl_xor(p, 8, 16);
            p += __shfl_xor(p, 4, 16);
            p += __shfl_xor(p, 2, 16);
            p += __shfl_xor(p, 1, 16);
            float w = __expf(fmaf(p, 0.25f, eb1));
            den += w;
            acc = fmaf(w, vf, acc);
        }
        kvw0 = nkv0; eb0 = neb0;
        kvw1 = nkv1; eb1 = neb1;
        i += 2;
    }
    if (i < end) {   // odd tail: element i sits in slot 0
        float kf = __uint_as_float(kvw0 << 16);
        float vf = __uint_as_float(kvw0 & 0xFFFF0000u);
        float p = qj * kf;
        p += __shfl_xor(p, 8, 16);
        p += __shfl_xor(p, 4, 16);
        p += __shfl_xor(p, 2, 16);
        p += __shfl_xor(p, 1, 16);
        float w = __expf(fmaf(p, 0.25f, eb0));
        den += w;
        acc = fmaf(w, vf, acc);
    }
    aggn[(size_t)t * OUT_F + tid] = acc / (den + 1e-10f);
}

// ---------------- Output projection (in-place on d_out, per-block rows) ----------
__global__ __launch_bounds__(128)
void out_kernel(const float* __restrict__ aggn,
                const float* __restrict__ Wo, const float* __restrict__ bo,
                float* __restrict__ out, int n_nodes) {
    __shared__ float xs[NTO][OUT_F];
    const int col   = threadIdx.x;
    const int node0 = blockIdx.x * NTO;

    #pragma unroll
    for (int n = 0; n < NTO; ++n) {
        int node = node0 + n;
        xs[n][col] = (node < n_nodes) ? aggn[(size_t)node * OUT_F + col] : 0.f;
    }
    __syncthreads();

    float acc[NTO];
    #pragma unroll
    for (int n = 0; n < NTO; ++n) acc[n] = 0.f;

    for (int kk = 0; kk < OUT_F; ++kk) {
        float wv = Wo[kk * OUT_F + col];
        #pragma unroll
        for (int n = 0; n < NTO; ++n) acc[n] = fmaf(xs[n][kk], wv, acc[n]);
    }

    float b = bo[col];
    #pragma unroll
    for (int n = 0; n < NTO; ++n) {
        int node = node0 + n;
        if (node < n_nodes) out[(size_t)node * OUT_F + col] = acc[n] + b;
    }
}

extern "C" void kernel_launch(void* const* d_in, const int* in_sizes, int n_in,
                              void* d_out, int out_size, void* d_ws, size_t ws_size,
                              hipStream_t stream) {
    const float* x  = (const float*)d_in[0];
    const int*   ei = (const int*)  d_in[1];
    const float* ef = (const float*)d_in[2];
    const float* Wq = (const float*)d_in[3];
    const float* bq = (const float*)d_in[4];
    const float* Wk = (const float*)d_in[5];
    const float* bk = (const float*)d_in[6];
    const float* Wv = (const float*)d_in[7];
    const float* bv = (const float*)d_in[8];
    const float* We = (const float*)d_in[9];
    const float* be = (const float*)d_in[10];
    const float* Wo = (const float*)d_in[11];
    const float* bo = (const float*)d_in[12];
    float* out = (float*)d_out;

    const int n_nodes = in_sizes[0] / IN_F;
    const int n_edges = in_sizes[1] / 2;

    float*        ws    = (float*)d_ws;
    float*        q     = ws;                                           // [N,128] f32
    unsigned int* kvp   = (unsigned int*)(q + (size_t)n_nodes * OUT_F); // [N,128] bf16 k|v
    float*        ebias = (float*)(kvp + (size_t)n_nodes * OUT_F);      // [E,8] f32
    int*          deg      = (int*)(ebias + (size_t)n_edges * HEADS);
    int*          rowstart = deg + n_nodes;                             // [N+1]
    int*          cursor   = rowstart + n_nodes + 1;                    // [N]
    int2*         csr2     = (int2*)(cursor + n_nodes);                 // [E] (src, edge)

    hipMemsetAsync(deg, 0, (size_t)n_nodes * sizeof(int), stream);

    qkv_kernel<<<(n_nodes + NTQ - 1) / NTQ, 128, 0, stream>>>(
        x, Wq, bq, Wk, bk, Wv, bv, q, kvp, n_nodes);

    ebias_kernel<<<(n_edges + 255) / 256, 256, 0, stream>>>(ef, We, be, ebias, n_edges);

    dim3 edgeGrid((n_edges + 255) / 256);
    count_kernel<<<edgeGrid, 256, 0, stream>>>(ei, deg, n_edges);
    scan_kernel<<<1, 1024, 0, stream>>>(deg, rowstart, cursor, n_nodes, n_edges);
    scatter_kernel<<<edgeGrid, 256, 0, stream>>>(ei, cursor, csr2, n_edges);

    // aggn written into d_out (scratch); out_kernel reads-then-overwrites per block
    agg_kernel<<<n_nodes, 128, 0, stream>>>(csr2, rowstart, q, kvp, ebias, out);

    out_kernel<<<(n_nodes + NTO - 1) / NTO, 128, 0, stream>>>(out, Wo, bo, out, n_nodes);
}

// Round 5
// 514.489 us; speedup vs baseline: 11.8668x; 1.4207x over previous
//
#include <hip/hip_runtime.h>
#include <hip/hip_bf16.h>
#include <math.h>

#define IN_F   128
#define OUT_F  128
#define HEADS  8
#define HEAD_D 16
#define EDGE_F 64
#define BUCKET 64     // CSR bucket capacity per node

typedef __attribute__((ext_vector_type(8))) short bf16x8;
typedef __attribute__((ext_vector_type(4))) float f32x4;

// round-to-nearest-even fp32 -> bf16 bits
__device__ inline unsigned int f2bf(float f) {
    union { float f; unsigned int u; } c; c.f = f;
    unsigned int r = c.u + 0x7FFFu + ((c.u >> 16) & 1u);
    return r >> 16;
}

// ---- Weight prep: swizzle Wq/Wk/Wv/Wo (fp32 [128][128]) into MFMA B-frag layout ----
// Wb[((mat*8+ct)*4+kb)*64 + lane] = 8 bf16: W[kb*32+(lane>>4)*8+j][ct*16+(lane&15)]
__global__ __launch_bounds__(256)
void wprep_kernel(const float* __restrict__ Wq, const float* __restrict__ Wk,
                  const float* __restrict__ Wv, const float* __restrict__ Wo,
                  uint4* __restrict__ Wb) {
    int id = blockIdx.x * 256 + threadIdx.x;     // 4*8*4*64 = 8192
    if (id >= 8192) return;
    int lane = id & 63;
    int kb   = (id >> 6) & 3;
    int ct   = (id >> 8) & 7;
    int mat  = id >> 11;
    const float* W = (mat == 0) ? Wq : (mat == 1) ? Wk : (mat == 2) ? Wv : Wo;
    int n  = ct * 16 + (lane & 15);
    int k0 = kb * 32 + (lane >> 4) * 8;
    unsigned int t[8];
    #pragma unroll
    for (int j = 0; j < 8; ++j) t[j] = f2bf(W[(size_t)(k0 + j) * 128 + n]);
    uint4 val;
    val.x = t[0] | (t[1] << 16);
    val.y = t[2] | (t[3] << 16);
    val.z = t[4] | (t[5] << 16);
    val.w = t[6] | (t[7] << 16);
    Wb[id] = val;
}

// ---- QKV via MFMA: q fp32, k/v packed bf16. 256 thr = 4 waves, 64 nodes/block ----
__global__ __launch_bounds__(256)
void qkv_mfma(const float* __restrict__ x, const bf16x8* __restrict__ WbV,
              const float* __restrict__ bq, const float* __restrict__ bk,
              const float* __restrict__ bv,
              float* __restrict__ q, unsigned int* __restrict__ kvp, int n_nodes) {
    const int tid  = threadIdx.x;
    const int wave = tid >> 6;
    const int lane = tid & 63;
    const int quad = lane >> 4;
    const int lcol = lane & 15;
    const int row0 = blockIdx.x * 64 + wave * 16;
    const int m    = row0 + lcol;                 // A-row this lane loads

    bf16x8 afrag[4];
    const bool mv = (m < n_nodes);
    const float* xr = x + (size_t)m * IN_F;
    #pragma unroll
    for (int kb = 0; kb < 4; ++kb) {
        float buf[8];
        if (mv) {
            float4 a = ((const float4*)(xr + kb * 32 + quad * 8))[0];
            float4 b = ((const float4*)(xr + kb * 32 + quad * 8 + 4))[0];
            buf[0]=a.x; buf[1]=a.y; buf[2]=a.z; buf[3]=a.w;
            buf[4]=b.x; buf[5]=b.y; buf[6]=b.z; buf[7]=b.w;
        } else {
            #pragma unroll
            for (int j = 0; j < 8; ++j) buf[j] = 0.f;
        }
        bf16x8 f;
        #pragma unroll
        for (int j = 0; j < 8; ++j) f[j] = (short)f2bf(buf[j]);
        afrag[kb] = f;
    }

    #pragma unroll
    for (int ct = 0; ct < 8; ++ct) {
        f32x4 aq = {0.f,0.f,0.f,0.f}, ak = {0.f,0.f,0.f,0.f}, av = {0.f,0.f,0.f,0.f};
        #pragma unroll
        for (int kb = 0; kb < 4; ++kb) {
            bf16x8 bq_ = WbV[((0 * 8 + ct) * 4 + kb) * 64 + lane];
            bf16x8 bk_ = WbV[((1 * 8 + ct) * 4 + kb) * 64 + lane];
            bf16x8 bv_ = WbV[((2 * 8 + ct) * 4 + kb) * 64 + lane];
            aq = __builtin_amdgcn_mfma_f32_16x16x32_bf16(afrag[kb], bq_, aq, 0, 0, 0);
            ak = __builtin_amdgcn_mfma_f32_16x16x32_bf16(afrag[kb], bk_, ak, 0, 0, 0);
            av = __builtin_amdgcn_mfma_f32_16x16x32_bf16(afrag[kb], bv_, av, 0, 0, 0);
        }
        const int col = ct * 16 + lcol;
        float bqc = bq[col], bkc = bk[col], bvc = bv[col];
        #pragma unroll
        for (int r = 0; r < 4; ++r) {
            int node = row0 + quad * 4 + r;       // C/D: row = quad*4+reg, col = lane&15
            if (node < n_nodes) {
                size_t o = (size_t)node * OUT_F + col;
                q[o]   = aq[r] + bqc;
                kvp[o] = f2bf(ak[r] + bkc) | (f2bf(av[r] + bvc) << 16);
            }
        }
    }
}

// ---- Edge bias: 1 thread/edge, direct float4 reads ----
__global__ __launch_bounds__(256)
void ebias_kernel(const float* __restrict__ ef,
                  const float* __restrict__ We, const float* __restrict__ be,
                  float* __restrict__ ebias, int n_edges) {
    __shared__ float sWe[EDGE_F * HEADS];
    __shared__ float sbe[HEADS];
    const int tid = threadIdx.x;
    for (int i = tid; i < EDGE_F * HEADS; i += 256) sWe[i] = We[i];
    if (tid < HEADS) sbe[tid] = be[tid];
    __syncthreads();

    const int e = blockIdx.x * 256 + tid;
    if (e >= n_edges) return;

    float acc[HEADS];
    #pragma unroll
    for (int h = 0; h < HEADS; ++h) acc[h] = sbe[h];

    const float4* er = (const float4*)(ef + (size_t)e * EDGE_F);
    #pragma unroll
    for (int j4 = 0; j4 < EDGE_F / 4; ++j4) {
        float4 evv = er[j4];
        float ev[4] = {evv.x, evv.y, evv.z, evv.w};
        #pragma unroll
        for (int jj = 0; jj < 4; ++jj) {
            int j = j4 * 4 + jj;
            #pragma unroll
            for (int h = 0; h < HEADS; ++h)
                acc[h] = fmaf(ev[jj], sWe[j * HEADS + h], acc[h]);
        }
    }
    float4* dst = (float4*)(ebias + (size_t)e * HEADS);
    dst[0] = make_float4(acc[0], acc[1], acc[2], acc[3]);
    dst[1] = make_float4(acc[4], acc[5], acc[6], acc[7]);
}

// ---- Bucketed CSR build: one pass, no scan ----
__global__ __launch_bounds__(256)
void scatter_kernel(const int* __restrict__ ei, int* __restrict__ deg,
                    int2* __restrict__ csr2, int n_edges) {
    int e = blockIdx.x * 256 + threadIdx.x;
    if (e < n_edges) {
        int s = ei[e];
        int t = ei[n_edges + e];
        int pos = atomicAdd(&deg[t], 1);
        if (pos < BUCKET) csr2[((size_t)t << 6) + pos] = make_int2(s, e);
    }
}

// ---- Aggregation: one block (128 thr) per target, 2-edge pipeline, bf16 out ----
__global__ __launch_bounds__(128)
void agg_kernel(const int2* __restrict__ csr2, const int* __restrict__ deg,
                const float* __restrict__ q, const unsigned int* __restrict__ kvp,
                const float* __restrict__ ebias, unsigned short* __restrict__ aggn) {
    const int t   = blockIdx.x;
    const int tid = threadIdx.x;        // feature index 0..127
    const int h   = tid >> 4;
    const float qj = q[(size_t)t * OUT_F + tid];

    const int beg = t << 6;
    int cnt = deg[t]; if (cnt > BUCKET) cnt = BUCKET;
    const int end = beg + cnt;

    float acc = 0.f, den = 0.f;

    unsigned int kvw0 = 0, kvw1 = 0;
    float eb0 = 0.f, eb1 = 0.f;
    if (beg < end) {
        int2 se = csr2[beg];
        kvw0 = kvp[(size_t)se.x * OUT_F + tid];
        eb0  = ebias[(size_t)se.y * HEADS + h];
    }
    if (beg + 1 < end) {
        int2 se = csr2[beg + 1];
        kvw1 = kvp[(size_t)se.x * OUT_F + tid];
        eb1  = ebias[(size_t)se.y * HEADS + h];
    }

    int i = beg;
    while (i + 1 < end) {
        unsigned int nkv0 = 0, nkv1 = 0;
        float neb0 = 0.f, neb1 = 0.f;
        if (i + 2 < end) {
            int2 se = csr2[i + 2];
            nkv0 = kvp[(size_t)se.x * OUT_F + tid];
            neb0 = ebias[(size_t)se.y * HEADS + h];
        }
        if (i + 3 < end) {
            int2 se = csr2[i + 3];
            nkv1 = kvp[(size_t)se.x * OUT_F + tid];
            neb1 = ebias[(size_t)se.y * HEADS + h];
        }
        {
            float kf = __uint_as_float(kvw0 << 16);
            float vf = __uint_as_float(kvw0 & 0xFFFF0000u);
            float p = qj * kf;
            p += __shfl_xor(p, 8, 16);
            p += __shfl_xor(p, 4, 16);
            p += __shfl_xor(p, 2, 16);
            p += __shfl_xor(p, 1, 16);
            float w = __expf(fmaf(p, 0.25f, eb0));
            den += w;
            acc = fmaf(w, vf, acc);
        }
        {
            float kf = __uint_as_float(kvw1 << 16);
            float vf = __uint_as_float(kvw1 & 0xFFFF0000u);
            float p = qj * kf;
            p += __shfl_xor(p, 8, 16);
            p += __shfl_xor(p, 4, 16);
            p += __shfl_xor(p, 2, 16);
            p += __shfl_xor(p, 1, 16);
            float w = __expf(fmaf(p, 0.25f, eb1));
            den += w;
            acc = fmaf(w, vf, acc);
        }
        kvw0 = nkv0; eb0 = neb0;
        kvw1 = nkv1; eb1 = neb1;
        i += 2;
    }
    if (i < end) {
        float kf = __uint_as_float(kvw0 << 16);
        float vf = __uint_as_float(kvw0 & 0xFFFF0000u);
        float p = qj * kf;
        p += __shfl_xor(p, 8, 16);
        p += __shfl_xor(p, 4, 16);
        p += __shfl_xor(p, 2, 16);
        p += __shfl_xor(p, 1, 16);
        float w = __expf(fmaf(p, 0.25f, eb0));
        den += w;
        acc = fmaf(w, vf, acc);
    }
    aggn[(size_t)t * OUT_F + tid] = (unsigned short)f2bf(acc / (den + 1e-10f));
}

// ---- Output projection via MFMA: aggn (bf16) @ Wo + bo ----
__global__ __launch_bounds__(256)
void out_mfma(const unsigned short* __restrict__ aggn, const bf16x8* __restrict__ WbV,
              const float* __restrict__ bo, float* __restrict__ out, int n_nodes) {
    const int tid  = threadIdx.x;
    const int wave = tid >> 6;
    const int lane = tid & 63;
    const int quad = lane >> 4;
    const int lcol = lane & 15;
    const int row0 = blockIdx.x * 64 + wave * 16;
    const int m    = row0 + lcol;

    bf16x8 afrag[4];
    const bool mv = (m < n_nodes);
    const bf16x8* ar = (const bf16x8*)(aggn + (size_t)m * OUT_F);
    #pragma unroll
    for (int kb = 0; kb < 4; ++kb) {
        if (mv) afrag[kb] = ar[kb * 4 + quad];
        else {
            bf16x8 z;
            #pragma unroll
            for (int j = 0; j < 8; ++j) z[j] = 0;
            afrag[kb] = z;
        }
    }

    #pragma unroll
    for (int ct = 0; ct < 8; ++ct) {
        f32x4 acc = {0.f, 0.f, 0.f, 0.f};
        #pragma unroll
        for (int kb = 0; kb < 4; ++kb) {
            bf16x8 b = WbV[((3 * 8 + ct) * 4 + kb) * 64 + lane];
            acc = __builtin_amdgcn_mfma_f32_16x16x32_bf16(afrag[kb], b, acc, 0, 0, 0);
        }
        const int col = ct * 16 + lcol;
        float boc = bo[col];
        #pragma unroll
        for (int r = 0; r < 4; ++r) {
            int node = row0 + quad * 4 + r;
            if (node < n_nodes) out[(size_t)node * OUT_F + col] = acc[r] + boc;
        }
    }
}

extern "C" void kernel_launch(void* const* d_in, const int* in_sizes, int n_in,
                              void* d_out, int out_size, void* d_ws, size_t ws_size,
                              hipStream_t stream) {
    const float* x  = (const float*)d_in[0];
    const int*   ei = (const int*)  d_in[1];
    const float* ef = (const float*)d_in[2];
    const float* Wq = (const float*)d_in[3];
    const float* bq = (const float*)d_in[4];
    const float* Wk = (const float*)d_in[5];
    const float* bk = (const float*)d_in[6];
    const float* Wv = (const float*)d_in[7];
    const float* bv = (const float*)d_in[8];
    const float* We = (const float*)d_in[9];
    const float* be = (const float*)d_in[10];
    const float* Wo = (const float*)d_in[11];
    const float* bo = (const float*)d_in[12];
    float* out = (float*)d_out;

    const int n_nodes = in_sizes[0] / IN_F;
    const int n_edges = in_sizes[1] / 2;

    char* w = (char*)d_ws;
    float*          q     = (float*)w;          w += (size_t)n_nodes * OUT_F * 4;
    unsigned int*   kvp   = (unsigned int*)w;   w += (size_t)n_nodes * OUT_F * 4;
    float*          ebias = (float*)w;          w += (size_t)n_edges * HEADS * 4;
    unsigned short* aggn  = (unsigned short*)w; w += (size_t)n_nodes * OUT_F * 2;
    uint4*          Wb    = (uint4*)w;          w += (size_t)8192 * 16;
    int*            deg   = (int*)w;            w += (size_t)n_nodes * 4;
    int2*           csr2  = (int2*)w;           // [N*64] (src, edge)

    hipMemsetAsync(deg, 0, (size_t)n_nodes * sizeof(int), stream);

    wprep_kernel<<<32, 256, 0, stream>>>(Wq, Wk, Wv, Wo, Wb);

    qkv_mfma<<<(n_nodes + 63) / 64, 256, 0, stream>>>(
        x, (const bf16x8*)Wb, bq, bk, bv, q, kvp, n_nodes);

    ebias_kernel<<<(n_edges + 255) / 256, 256, 0, stream>>>(ef, We, be, ebias, n_edges);

    scatter_kernel<<<(n_edges + 255) / 256, 256, 0, stream>>>(ei, deg, csr2, n_edges);

    agg_kernel<<<n_nodes, 128, 0, stream>>>(csr2, deg, q, kvp, ebias, aggn);

    out_mfma<<<(n_nodes + 63) / 64, 256, 0, stream>>>(aggn, (const bf16x8*)Wb, bo, out, n_nodes);
}